// Round 16
// baseline (424.639 us; speedup 1.0000x reference)
//
#include <hip/hip_runtime.h>
#include <hip/hip_bf16.h>

#define NN 10000
#define NE 320000
#define HD 128
#define TILE 128
#define NTILES (NE / TILE)   // 2500 exactly

typedef __attribute__((ext_vector_type(8))) short s16x8;
typedef __attribute__((ext_vector_type(4))) short s16x4;
typedef __attribute__((ext_vector_type(4))) float f32x4;

__device__ __forceinline__ ushort f2bf(float f) {
    union { __hip_bfloat16 b; ushort u; } v;
    v.b = __float2bfloat16(f);   // HW cvt (RNE) on gfx950
    return v.u;
}
__device__ __forceinline__ float bf2f(short s) {
    union { unsigned u; float f; } v;
    v.u = ((unsigned)(unsigned short)s) << 16;
    return v.f;
}

struct WPtrs { const float* w[8]; const float* w0[3]; };

// ---------------- fused prep: nodeAB block-0 + weight prep + cnt zero ----------------
__global__ __launch_bounds__(256)
void prep_kernel(const float* __restrict__ x, const float* __restrict__ W00,
                 const float* __restrict__ b00, ushort* __restrict__ A,
                 ushort* __restrict__ Bm, float* __restrict__ x0,
                 WPtrs p, ushort* __restrict__ wdst, int* __restrict__ cnt) {
    __shared__ float xs[16 * 128];
    const int blk = blockIdx.x;
    const int t = threadIdx.x;
    if (blk < 625) {
        const int n0 = blk * 16;
        for (int i = t; i < 16 * 4; i += 256) {
            int n = i / 4, d = i % 4;
            xs[n * 128 + d] = x[(size_t)(n0 + n) * 4 + d];
        }
        for (int i = t; i < 16 * 128; i += 256) x0[(size_t)n0 * 128 + i] = 0.f;
        __syncthreads();
        int c = t & 127;
        int h = t >> 7;
        float a[8], b[8];
        float bias = b00[c];
#pragma unroll
        for (int n = 0; n < 8; n++) { a[n] = bias; b[n] = 0.f; }
#pragma unroll
        for (int d = 0; d < 4; d++) {
            float wt = W00[d * HD + c];
            float wb = W00[(4 + d) * HD + c];
            float wd = wt - wb;
#pragma unroll
            for (int n = 0; n < 8; n++) {
                float xv = xs[(h * 8 + n) * 128 + d];
                a[n] += xv * wd;
                b[n] += xv * wb;
            }
        }
#pragma unroll
        for (int n = 0; n < 8; n++) {
            int gn = n0 + h * 8 + n;
            A[(size_t)gn * HD + c] = f2bf(a[n]);
            Bm[(size_t)gn * HD + c] = f2bf(b[n]);
        }
    } else if (blk < 1465) {
        int tid = (blk - 625) * 256 + t;
        if (tid < 7 * 16384) {
            int m = tid >> 14, idx = tid & 16383;
            int b = m >> 1, l = m & 1;
            int k = idx / 128, c = idx % 128;
            wdst[l * 65536 + b * 16384 + c * 128 + k] = f2bf(p.w[m][k * 128 + c]);
        } else if (tid < 7 * 16384 + 2048) {
            int idx = tid - 7 * 16384;
            int k = idx / 16, c = idx % 16;
            wdst[65536 + 3 * 16384 + c * 128 + k] = f2bf(p.w[7][k * 16 + c]);
        } else {
            int q = tid - 116736;
            int b = q >> 15, r = q & 32767;
            int cc = r >> 7, d = r & 127;
            const float* w0 = p.w0[b];
            float val = (cc < 128) ? (w0[d * 128 + cc] - w0[(128 + d) * 128 + cc])
                                   : w0[(128 + d) * 128 + (cc - 128)];
            wdst[131072 + b * 32768 + cc * 128 + d] = f2bf(val);
        }
    } else {
        int i = (blk - 1465) * 256 + t;
        if (i < NN) cnt[i] = 0;
    }
}

// ---------------- CSR build (edges sorted by dst) ----------------
__global__ void hist_kernel(const int* __restrict__ dst, int* __restrict__ cnt) {
    int e = blockIdx.x * blockDim.x + threadIdx.x;
    if (e < NE) atomicAdd(&cnt[dst[e]], 1);
}

__global__ void scan_kernel(const int* __restrict__ cnt, int* __restrict__ rs, int* __restrict__ cur) {
    __shared__ int part[256];
    int t = threadIdx.x;
    const int CH = (NN + 255) / 256;  // 40
    int base = t * CH;
    int s = 0;
    for (int i = 0; i < CH; i++) {
        int idx = base + i;
        if (idx < NN) s += cnt[idx];
    }
    part[t] = s;
    __syncthreads();
    for (int off = 1; off < 256; off <<= 1) {
        int v = (t >= off) ? part[t - off] : 0;
        __syncthreads();
        part[t] += v;
        __syncthreads();
    }
    int run = part[t] - s;
    for (int i = 0; i < CH; i++) {
        int idx = base + i;
        if (idx < NN) {
            rs[idx] = run;
            cur[idx] = run;
            run += cnt[idx];
        }
    }
    if (t == 255) rs[NN] = run;
}

__global__ void scatter_kernel(const int* __restrict__ src, const int* __restrict__ dst,
                               int* __restrict__ cur, int* __restrict__ ssrc,
                               int* __restrict__ nof) {
    int e = blockIdx.x * blockDim.x + threadIdx.x;
    if (e < NE) {
        int d = dst[e];
        int p = atomicAdd(&cur[d], 1);
        ssrc[p] = src[e];
        nof[p] = d;
    }
}

// ---------------- blocks 1-3 layer-1 via MFMA: 32 nodes/block x 256 outs x K=128 ----------------
__global__ __launch_bounds__(256)
void nodeAB_mfma_kernel(const float* __restrict__ xin, const ushort* __restrict__ WAB,
                        const float* __restrict__ b0, ushort* __restrict__ A,
                        ushort* __restrict__ Bm, float* __restrict__ zbuf, int ZD) {
    __shared__ __align__(16) ushort xs[32 * 136];
    const int t = threadIdx.x, lane = t & 63, w = t >> 6, lr = lane & 15, lg = lane >> 4;
    const int n0 = blockIdx.x * 32;

    for (int i = t; i < 1024; i += 256) {
        const int n = i >> 5, s4 = i & 31;
        const float4 xv = *(const float4*)(xin + (size_t)(n0 + n) * HD + s4 * 4);
        s16x4 hx;
        hx[0] = f2bf(xv.x); hx[1] = f2bf(xv.y); hx[2] = f2bf(xv.z); hx[3] = f2bf(xv.w);
        *(s16x4*)(xs + n * 136 + s4 * 4) = hx;
    }
    for (int i = t; i < 32 * ZD; i += 256) {
        const int n = i / ZD;
        if (n0 + n < NN) zbuf[(size_t)n0 * ZD + i] = 0.f;
    }
    __syncthreads();

    s16x8 wf[4][4];
#pragma unroll
    for (int nt = 0; nt < 4; nt++)
#pragma unroll
        for (int ks = 0; ks < 4; ks++)
            wf[nt][ks] = *(const s16x8*)(WAB + (size_t)(w * 64 + nt * 16 + lr) * HD + ks * 32 + lg * 8);

    f32x4 acc[2][4];
#pragma unroll
    for (int nt = 0; nt < 4; nt++) {
        const int cc = w * 64 + nt * 16 + lr;
        const float bb = (cc < 128) ? b0[cc] : 0.f;
        f32x4 v; v[0] = bb; v[1] = bb; v[2] = bb; v[3] = bb;
        acc[0][nt] = v;
        acc[1][nt] = v;
    }
#pragma unroll
    for (int ks = 0; ks < 4; ks++) {
#pragma unroll
        for (int g = 0; g < 2; g++) {
            const s16x8 xf = *(const s16x8*)(xs + (g * 16 + lr) * 136 + ks * 32 + lg * 8);
#pragma unroll
            for (int nt = 0; nt < 4; nt++)
                acc[g][nt] = __builtin_amdgcn_mfma_f32_16x16x32_bf16(xf, wf[nt][ks], acc[g][nt], 0, 0, 0);
        }
    }
#pragma unroll
    for (int g = 0; g < 2; g++)
#pragma unroll
        for (int nt = 0; nt < 4; nt++) {
            const int cc = w * 64 + nt * 16 + lr;
#pragma unroll
            for (int r = 0; r < 4; r++) {
                const int node = n0 + g * 16 + lg * 4 + r;
                if (node < NN) {
                    const ushort val = f2bf(acc[g][nt][r]);
                    if (cc < 128) A[(size_t)node * HD + cc] = val;
                    else Bm[(size_t)node * HD + (cc - 128)] = val;
                }
            }
        }
}

// ---------------- persistent MFMA edge kernel: 2x2 wave split (halved LDS reads) ----------------
// Wave w: we = w>>1 (e-half), wc = w&1 (c-half).
// L2: D[c][e], c in [wc*64,+64), e in [we*64,+64)   acc[4 mt][4 nt]
// L3: D[e][cout], e in [we*64,+64), cout in [wc*64,+64)  acc3[4 nt][4 ct]  (DOUTB=128)
// AGG: unchanged (wave w reads m rows c in [w*32,+32), all e) -- needs B3 (cross-wave).
// C/D frag: col = lane&15 (B-operand row), row = (lane>>4)*4 + reg (A-operand row)  [m89/m91]
template<int DOUTB>
__global__ __launch_bounds__(256, 2)
void edge_mfma_kernel(const ushort* __restrict__ Af, const ushort* __restrict__ Bf,
                      const ushort* __restrict__ W1T, const float* __restrict__ b1,
                      const ushort* __restrict__ W2T, const float* __restrict__ b2,
                      const int* __restrict__ ssrc, const int* __restrict__ nof,
                      float* __restrict__ out) {
    __shared__ __align__(16) ushort HH1[TILE * 136];   // h1 [e][k]; later m [c][e]
    __shared__ __align__(16) ushort HH2[TILE * 136];   // h2 [e][c]
    __shared__ __align__(16) int s_node[2][TILE];

    const int t = threadIdx.x;
    const int lane = t & 63;
    const int w = t >> 6;
    const int lr = lane & 15;
    const int lg = lane >> 4;
    const int we = w >> 1;      // e-half
    const int wc = w & 1;       // c-half
    const int cg = t & 15;      // gather k-chunk
    const int eb = t >> 4;      // gather base edge (e_i = eb + 16*i)

    // ---- persistent weight fragments (once per block) ----
    s16x8 w1f[4][4];   // c-rows wc*64 + mt*16 + lr
#pragma unroll
    for (int mt = 0; mt < 4; mt++)
#pragma unroll
        for (int ks = 0; ks < 4; ks++)
            w1f[mt][ks] = *(const s16x8*)(W1T + (size_t)(wc * 64 + mt * 16 + lr) * HD + ks * 32 + lg * 8);

    constexpr int CT3 = (DOUTB == 128) ? 4 : 1;
    s16x8 w2f[CT3][4];
#pragma unroll
    for (int ct = 0; ct < CT3; ct++) {
        const int row = (DOUTB == 128) ? (wc * 64 + ct * 16 + lr) : lr;
#pragma unroll
        for (int ks = 0; ks < 4; ks++)
            w2f[ct][ks] = *(const s16x8*)(W2T + (size_t)row * HD + ks * 32 + lg * 8);
    }

    float bias2[4][4];
#pragma unroll
    for (int mt = 0; mt < 4; mt++)
#pragma unroll
        for (int r = 0; r < 4; r++)
            bias2[mt][r] = b1[wc * 64 + mt * 16 + lg * 4 + r];
    float bias3[CT3];
#pragma unroll
    for (int ct = 0; ct < CT3; ct++)
        bias3[ct] = (DOUTB == 128) ? b2[wc * 64 + ct * 16 + lr] : b2[lr];

    // ---- prologue: tile-0 indices + bv gathers ----
    int tile = blockIdx.x;
    int ts = tile * TILE;
    if (t < TILE) s_node[0][t] = nof[ts + t];
    int nd[8], sr[8];
#pragma unroll
    for (int i = 0; i < 8; i++) {
        const int e = eb + 16 * i;
        nd[i] = nof[ts + e];
        sr[i] = ssrc[ts + e];
    }
    s16x8 bv[8];
#pragma unroll
    for (int i = 0; i < 8; i++)
        bv[i] = *(const s16x8*)(Bf + (size_t)sr[i] * HD + cg * 8);
    int buf = 0;
    __syncthreads();

    for (; tile < NTILES; tile += gridDim.x) {
        ts = tile * TILE;
        const int tn = (tile + (int)gridDim.x < NTILES) ? (tile + (int)gridDim.x) : tile;
        const int tsn = tn * TILE;

        // ---- h1 fill: av on demand (dst-sorted -> L1-hot), bv prefetched ----
#pragma unroll
        for (int i = 0; i < 8; i++) {
            const int e = eb + 16 * i;
            const s16x8 av = *(const s16x8*)(Af + (size_t)nd[i] * HD + cg * 8);
            s16x8 hv;
#pragma unroll
            for (int j = 0; j < 8; j++)
                hv[j] = f2bf(fmaxf(bf2f(av[j]) + bf2f(bv[i][j]), 0.f));
            *(s16x8*)(HH1 + e * 136 + cg * 8) = hv;
        }
        __syncthreads();   // B1: h1 visible

        // ---- prefetch next-tile indices + s_node[buf^1] (land during L2) ----
#pragma unroll
        for (int i = 0; i < 8; i++) {
            const int e = eb + 16 * i;
            nd[i] = nof[tsn + e];
            sr[i] = ssrc[tsn + e];
        }
        if (t < TILE) s_node[buf ^ 1][t] = nof[tsn + t];

        // ---- layer 2: D[c][e], wave's c-half x e-half ----
        f32x4 acc[4][4];
#pragma unroll
        for (int mt = 0; mt < 4; mt++)
#pragma unroll
            for (int nt = 0; nt < 4; nt++) {
                f32x4 v; v[0] = bias2[mt][0]; v[1] = bias2[mt][1]; v[2] = bias2[mt][2]; v[3] = bias2[mt][3];
                acc[mt][nt] = v;
            }
#pragma unroll
        for (int ks = 0; ks < 4; ks++) {
            const int k0 = ks * 32 + lg * 8;
            s16x8 bfr[4];
#pragma unroll
            for (int nt = 0; nt < 4; nt++)
                bfr[nt] = *(const s16x8*)(HH1 + (we * 64 + nt * 16 + lr) * 136 + k0);
#pragma unroll
            for (int mt = 0; mt < 4; mt++)
#pragma unroll
                for (int nt = 0; nt < 4; nt++)
                    acc[mt][nt] = __builtin_amdgcn_mfma_f32_16x16x32_bf16(w1f[mt][ks], bfr[nt], acc[mt][nt], 0, 0, 0);
        }
        // h2 = relu(acc) -> HH2[e][c]
#pragma unroll
        for (int mt = 0; mt < 4; mt++)
#pragma unroll
            for (int nt = 0; nt < 4; nt++) {
                const int e = we * 64 + nt * 16 + lr;
                const int c0 = wc * 64 + mt * 16 + lg * 4;
                s16x4 hv;
                hv[0] = f2bf(fmaxf(acc[mt][nt][0], 0.f));
                hv[1] = f2bf(fmaxf(acc[mt][nt][1], 0.f));
                hv[2] = f2bf(fmaxf(acc[mt][nt][2], 0.f));
                hv[3] = f2bf(fmaxf(acc[mt][nt][3], 0.f));
                *(s16x4*)(HH2 + e * 136 + c0) = hv;
            }
        // ---- issue next-tile bv gathers (land during L3+agg) ----
#pragma unroll
        for (int i = 0; i < 8; i++)
            bv[i] = *(const s16x8*)(Bf + (size_t)sr[i] * HD + cg * 8);
        __syncthreads();   // B2: h2 visible; HH1 reads retired

        // ---- layer 3 (swapped operands): D[e][cout]; m -> HH1 ----
        if constexpr (DOUTB == 128) {
            f32x4 acc3[4][4];
#pragma unroll
            for (int nt = 0; nt < 4; nt++)
#pragma unroll
                for (int ct = 0; ct < 4; ct++) {
                    const float bb = bias3[ct];
                    f32x4 v; v[0] = bb; v[1] = bb; v[2] = bb; v[3] = bb;
                    acc3[nt][ct] = v;
                }
#pragma unroll
            for (int ks = 0; ks < 4; ks++) {
                const int k0 = ks * 32 + lg * 8;
                s16x8 h2f[4];
#pragma unroll
                for (int nt = 0; nt < 4; nt++)
                    h2f[nt] = *(const s16x8*)(HH2 + (we * 64 + nt * 16 + lr) * 136 + k0);
#pragma unroll
                for (int nt = 0; nt < 4; nt++)
#pragma unroll
                    for (int ct = 0; ct < 4; ct++)
                        acc3[nt][ct] = __builtin_amdgcn_mfma_f32_16x16x32_bf16(h2f[nt], w2f[ct][ks], acc3[nt][ct], 0, 0, 0);
            }
#pragma unroll
            for (int nt = 0; nt < 4; nt++)
#pragma unroll
                for (int ct = 0; ct < 4; ct++) {
                    const int e0 = we * 64 + nt * 16 + lg * 4;
                    const int c = wc * 64 + ct * 16 + lr;
                    s16x4 mv;
                    mv[0] = f2bf(acc3[nt][ct][0]);
                    mv[1] = f2bf(acc3[nt][ct][1]);
                    mv[2] = f2bf(acc3[nt][ct][2]);
                    mv[3] = f2bf(acc3[nt][ct][3]);
                    *(s16x4*)(HH1 + c * 136 + e0) = mv;
                }
        } else {
            // DOUTB == 16: single cout-tile; waves split edges (e-tiles {2w, 2w+1})
            f32x4 acc3[2];
#pragma unroll
            for (int e2 = 0; e2 < 2; e2++) {
                const float bb = bias3[0];
                f32x4 v; v[0] = bb; v[1] = bb; v[2] = bb; v[3] = bb;
                acc3[e2] = v;
            }
#pragma unroll
            for (int ks = 0; ks < 4; ks++) {
                const int k0 = ks * 32 + lg * 8;
#pragma unroll
                for (int e2 = 0; e2 < 2; e2++) {
                    const s16x8 h2f = *(const s16x8*)(HH2 + ((w * 2 + e2) * 16 + lr) * 136 + k0);
                    acc3[e2] = __builtin_amdgcn_mfma_f32_16x16x32_bf16(h2f, w2f[0][ks], acc3[e2], 0, 0, 0);
                }
            }
#pragma unroll
            for (int e2 = 0; e2 < 2; e2++) {
                const int e0 = (w * 2 + e2) * 16 + lg * 4;
                const int c = lr;
                s16x4 mv;
                mv[0] = f2bf(acc3[e2][0]);
                mv[1] = f2bf(acc3[e2][1]);
                mv[2] = f2bf(acc3[e2][2]);
                mv[3] = f2bf(acc3[e2][3]);
                *(s16x4*)(HH1 + c * 136 + e0) = mv;
            }
        }
        __syncthreads();   // B3: m visible (agg reads cross-wave e-halves)

        // ---- aggregation via MFMA: out[slot][c] = Σ_e sel[slot][e] m[e][c] ----
        const int* sn = s_node[buf];
        const int nd0 = sn[0];
        const int ndL = sn[TILE - 1];
        if constexpr (DOUTB == 128) {
            if (ndL - nd0 <= 15) {
                f32x4 agg[2];
                agg[0] = (f32x4)0.f; agg[1] = (f32x4)0.f;
#pragma unroll
                for (int ks = 0; ks < 4; ks++) {
                    const int4 na = *(const int4*)&sn[ks * 32 + lg * 8];
                    const int4 nb = *(const int4*)&sn[ks * 32 + lg * 8 + 4];
                    s16x8 sel;
                    sel[0] = (na.x - nd0 == lr) ? (short)0x3F80 : (short)0;
                    sel[1] = (na.y - nd0 == lr) ? (short)0x3F80 : (short)0;
                    sel[2] = (na.z - nd0 == lr) ? (short)0x3F80 : (short)0;
                    sel[3] = (na.w - nd0 == lr) ? (short)0x3F80 : (short)0;
                    sel[4] = (nb.x - nd0 == lr) ? (short)0x3F80 : (short)0;
                    sel[5] = (nb.y - nd0 == lr) ? (short)0x3F80 : (short)0;
                    sel[6] = (nb.z - nd0 == lr) ? (short)0x3F80 : (short)0;
                    sel[7] = (nb.w - nd0 == lr) ? (short)0x3F80 : (short)0;
#pragma unroll
                    for (int ci = 0; ci < 2; ci++) {
                        const s16x8 mf = *(const s16x8*)(HH1 + ((w * 2 + ci) * 16 + lr) * 136 + ks * 32 + lg * 8);
                        agg[ci] = __builtin_amdgcn_mfma_f32_16x16x32_bf16(sel, mf, agg[ci], 0, 0, 0);
                    }
                }
#pragma unroll
                for (int ci = 0; ci < 2; ci++) {
                    const int c = (w * 2 + ci) * 16 + lr;
#pragma unroll
                    for (int r = 0; r < 4; r++) {
                        const int ndn = nd0 + lg * 4 + r;
                        if (ndn <= ndL) {
                            float* dp = out + (size_t)ndn * 128 + c;
                            const float v = agg[ci][r];
                            if (ndn > nd0 && ndn < ndL) *dp = v;
                            else atomicAdd(dp, v);
                        }
                    }
                }
            } else {
                for (int idx = t; idx < TILE * 128; idx += 256) {
                    const int e = idx >> 7, c = idx & 127;
                    atomicAdd(out + (size_t)sn[e] * 128 + c, bf2f(HH1[c * 136 + e]));
                }
            }
        } else {
            const int nw0 = sn[w * 32];
            const int nwL = sn[w * 32 + 31];
            if (nwL - nw0 <= 15) {
                const int4 na = *(const int4*)&sn[w * 32 + lg * 8];
                const int4 nb = *(const int4*)&sn[w * 32 + lg * 8 + 4];
                s16x8 sel;
                sel[0] = (na.x - nw0 == lr) ? (short)0x3F80 : (short)0;
                sel[1] = (na.y - nw0 == lr) ? (short)0x3F80 : (short)0;
                sel[2] = (na.z - nw0 == lr) ? (short)0x3F80 : (short)0;
                sel[3] = (na.w - nw0 == lr) ? (short)0x3F80 : (short)0;
                sel[4] = (nb.x - nw0 == lr) ? (short)0x3F80 : (short)0;
                sel[5] = (nb.y - nw0 == lr) ? (short)0x3F80 : (short)0;
                sel[6] = (nb.z - nw0 == lr) ? (short)0x3F80 : (short)0;
                sel[7] = (nb.w - nw0 == lr) ? (short)0x3F80 : (short)0;
                const s16x8 mf = *(const s16x8*)(HH1 + lr * 136 + w * 32 + lg * 8);
                f32x4 agg = (f32x4)0.f;
                agg = __builtin_amdgcn_mfma_f32_16x16x32_bf16(sel, mf, agg, 0, 0, 0);
#pragma unroll
                for (int r = 0; r < 4; r++) {
                    const int ndn = nw0 + lg * 4 + r;
                    if (ndn <= nwL) {
                        float* dp = out + (size_t)ndn * 16 + lr;
                        const float v = agg[r];
                        if (ndn > nw0 && ndn < nwL) *dp = v;
                        else atomicAdd(dp, v);
                    }
                }
            } else {
                for (int idx = lane; idx < 32 * 16; idx += 64) {
                    const int e = w * 32 + (idx >> 4), c = idx & 15;
                    atomicAdd(out + (size_t)sn[e] * 16 + c, bf2f(HH1[c * 136 + e]));
                }
            }
        }
        buf ^= 1;
        __syncthreads();   // B4: agg reads retired before next h1 fill
    }
}

extern "C" void kernel_launch(void* const* d_in, const int* in_sizes, int n_in,
                              void* d_out, int out_size, void* d_ws, size_t ws_size,
                              hipStream_t stream) {
    const float* x = (const float*)d_in[0];
    const int* ei = (const int*)d_in[2];
    const int* src = ei;
    const int* dst = ei + NE;
    const float* W[4][3];
    const float* bs[4][3];
    for (int b = 0; b < 4; b++)
        for (int l = 0; l < 3; l++) {
            W[b][l]  = (const float*)d_in[4 + b * 6 + l * 2];
            bs[b][l] = (const float*)d_in[4 + b * 6 + l * 2 + 1];
        }

    float* x0   = (float*)d_ws;
    float* x1   = x0 + (size_t)NN * HD;
    ushort* A   = (ushort*)(x1 + (size_t)NN * HD);
    ushort* Bm  = A + (size_t)NN * HD;
    ushort* WT  = Bm + (size_t)NN * HD;       // 229376 ushort = 448 KB
    int* cnt    = (int*)(WT + 229376);
    int* rs     = cnt + NN;
    int* cur    = rs + NN + 1;
    int* ssrc   = cur + NN;
    int* nof    = ssrc + NE;
    float* out  = (float*)d_out;

    WPtrs wp;
    for (int b = 0; b < 4; b++) { wp.w[2 * b] = W[b][1]; wp.w[2 * b + 1] = W[b][2]; }
    for (int b = 1; b < 4; b++) wp.w0[b - 1] = W[b][0];

    prep_kernel<<<1505, 256, 0, stream>>>(x, W[0][0], bs[0][0], A, Bm, x0, wp, WT, cnt);
    hist_kernel<<<(NE + 255) / 256, 256, 0, stream>>>(dst, cnt);
    scan_kernel<<<1, 256, 0, stream>>>(cnt, rs, cur);
    scatter_kernel<<<(NE + 255) / 256, 256, 0, stream>>>(src, dst, cur, ssrc, nof);

    const ushort* W1T[4];
    const ushort* W2T[4];
    const ushort* WAB[4];
    for (int b = 0; b < 4; b++) { W1T[b] = WT + b * 16384; W2T[b] = WT + 65536 + b * 16384; }
    for (int b = 1; b < 4; b++) WAB[b] = WT + 131072 + (b - 1) * 32768;

    const int EG = 500;   // 5 tiles/block, 2 blocks/CU

    edge_mfma_kernel<128><<<EG, 256, 0, stream>>>(A, Bm, W1T[0], bs[0][1], W2T[0], bs[0][2], ssrc, nof, x0);
    nodeAB_mfma_kernel<<<(NN + 31) / 32, 256, 0, stream>>>(x0, WAB[1], bs[1][0], A, Bm, x1, 128);
    edge_mfma_kernel<128><<<EG, 256, 0, stream>>>(A, Bm, W1T[1], bs[1][1], W2T[1], bs[1][2], ssrc, nof, x1);
    nodeAB_mfma_kernel<<<(NN + 31) / 32, 256, 0, stream>>>(x1, WAB[2], bs[2][0], A, Bm, x0, 128);
    edge_mfma_kernel<128><<<EG, 256, 0, stream>>>(A, Bm, W1T[2], bs[2][1], W2T[2], bs[2][2], ssrc, nof, x0);
    nodeAB_mfma_kernel<<<(NN + 31) / 32, 256, 0, stream>>>(x0, WAB[3], bs[3][0], A, Bm, out, 16);
    edge_mfma_kernel<16><<<EG, 256, 0, stream>>>(A, Bm, W1T[3], bs[3][1], W2T[3], bs[3][2], ssrc, nof, out);
}

// Round 17
// 259.412 us; speedup vs baseline: 1.6369x; 1.6369x over previous
//
#include <hip/hip_runtime.h>
#include <hip/hip_bf16.h>

#define NN 10000
#define NE 320000
#define HD 128
#define TILE 128
#define NTILES (NE / TILE)   // 2500 exactly

typedef __attribute__((ext_vector_type(8))) short s16x8;
typedef __attribute__((ext_vector_type(4))) short s16x4;
typedef __attribute__((ext_vector_type(4))) float f32x4;

__device__ __forceinline__ ushort f2bf(float f) {
    union { __hip_bfloat16 b; ushort u; } v;
    v.b = __float2bfloat16(f);   // HW cvt (RNE) on gfx950
    return v.u;
}
__device__ __forceinline__ float bf2f(short s) {
    union { unsigned u; float f; } v;
    v.u = ((unsigned)(unsigned short)s) << 16;
    return v.f;
}

struct WPtrs { const float* w[8]; const float* w0[3]; };

// ---------------- fused prep: nodeAB block-0 + weight prep + cnt zero ----------------
__global__ __launch_bounds__(256)
void prep_kernel(const float* __restrict__ x, const float* __restrict__ W00,
                 const float* __restrict__ b00, ushort* __restrict__ A,
                 ushort* __restrict__ Bm, float* __restrict__ x0,
                 WPtrs p, ushort* __restrict__ wdst, int* __restrict__ cnt) {
    __shared__ float xs[16 * 128];
    const int blk = blockIdx.x;
    const int t = threadIdx.x;
    if (blk < 625) {
        const int n0 = blk * 16;
        for (int i = t; i < 16 * 4; i += 256) {
            int n = i / 4, d = i % 4;
            xs[n * 128 + d] = x[(size_t)(n0 + n) * 4 + d];
        }
        for (int i = t; i < 16 * 128; i += 256) x0[(size_t)n0 * 128 + i] = 0.f;
        __syncthreads();
        int c = t & 127;
        int h = t >> 7;
        float a[8], b[8];
        float bias = b00[c];
#pragma unroll
        for (int n = 0; n < 8; n++) { a[n] = bias; b[n] = 0.f; }
#pragma unroll
        for (int d = 0; d < 4; d++) {
            float wt = W00[d * HD + c];
            float wb = W00[(4 + d) * HD + c];
            float wd = wt - wb;
#pragma unroll
            for (int n = 0; n < 8; n++) {
                float xv = xs[(h * 8 + n) * 128 + d];
                a[n] += xv * wd;
                b[n] += xv * wb;
            }
        }
#pragma unroll
        for (int n = 0; n < 8; n++) {
            int gn = n0 + h * 8 + n;
            A[(size_t)gn * HD + c] = f2bf(a[n]);
            Bm[(size_t)gn * HD + c] = f2bf(b[n]);
        }
    } else if (blk < 1465) {
        int tid = (blk - 625) * 256 + t;
        if (tid < 7 * 16384) {
            int m = tid >> 14, idx = tid & 16383;
            int b = m >> 1, l = m & 1;
            int k = idx / 128, c = idx % 128;
            wdst[l * 65536 + b * 16384 + c * 128 + k] = f2bf(p.w[m][k * 128 + c]);
        } else if (tid < 7 * 16384 + 2048) {
            int idx = tid - 7 * 16384;
            int k = idx / 16, c = idx % 16;
            wdst[65536 + 3 * 16384 + c * 128 + k] = f2bf(p.w[7][k * 16 + c]);
        } else {
            int q = tid - 116736;
            int b = q >> 15, r = q & 32767;
            int cc = r >> 7, d = r & 127;
            const float* w0 = p.w0[b];
            float val = (cc < 128) ? (w0[d * 128 + cc] - w0[(128 + d) * 128 + cc])
                                   : w0[(128 + d) * 128 + (cc - 128)];
            wdst[131072 + b * 32768 + cc * 128 + d] = f2bf(val);
        }
    } else {
        int i = (blk - 1465) * 256 + t;
        if (i < NN) cnt[i] = 0;
    }
}

// ---------------- CSR build (edges sorted by dst) ----------------
__global__ void hist_kernel(const int* __restrict__ dst, int* __restrict__ cnt) {
    int e = blockIdx.x * blockDim.x + threadIdx.x;
    if (e < NE) atomicAdd(&cnt[dst[e]], 1);
}

__global__ void scan_kernel(const int* __restrict__ cnt, int* __restrict__ rs, int* __restrict__ cur) {
    __shared__ int part[256];
    int t = threadIdx.x;
    const int CH = (NN + 255) / 256;  // 40
    int base = t * CH;
    int s = 0;
    for (int i = 0; i < CH; i++) {
        int idx = base + i;
        if (idx < NN) s += cnt[idx];
    }
    part[t] = s;
    __syncthreads();
    for (int off = 1; off < 256; off <<= 1) {
        int v = (t >= off) ? part[t - off] : 0;
        __syncthreads();
        part[t] += v;
        __syncthreads();
    }
    int run = part[t] - s;
    for (int i = 0; i < CH; i++) {
        int idx = base + i;
        if (idx < NN) {
            rs[idx] = run;
            cur[idx] = run;
            run += cnt[idx];
        }
    }
    if (t == 255) rs[NN] = run;
}

__global__ void scatter_kernel(const int* __restrict__ src, const int* __restrict__ dst,
                               int* __restrict__ cur, int* __restrict__ ssrc,
                               int* __restrict__ nof) {
    int e = blockIdx.x * blockDim.x + threadIdx.x;
    if (e < NE) {
        int d = dst[e];
        int p = atomicAdd(&cur[d], 1);
        ssrc[p] = src[e];
        nof[p] = d;
    }
}

// ---------------- blocks 1-3 layer-1 via MFMA: 32 nodes/block x 256 outs x K=128 ----------------
__global__ __launch_bounds__(256)
void nodeAB_mfma_kernel(const float* __restrict__ xin, const ushort* __restrict__ WAB,
                        const float* __restrict__ b0, ushort* __restrict__ A,
                        ushort* __restrict__ Bm, float* __restrict__ zbuf, int ZD) {
    __shared__ __align__(16) ushort xs[32 * 136];
    const int t = threadIdx.x, lane = t & 63, w = t >> 6, lr = lane & 15, lg = lane >> 4;
    const int n0 = blockIdx.x * 32;

    for (int i = t; i < 1024; i += 256) {
        const int n = i >> 5, s4 = i & 31;
        const float4 xv = *(const float4*)(xin + (size_t)(n0 + n) * HD + s4 * 4);
        s16x4 hx;
        hx[0] = f2bf(xv.x); hx[1] = f2bf(xv.y); hx[2] = f2bf(xv.z); hx[3] = f2bf(xv.w);
        *(s16x4*)(xs + n * 136 + s4 * 4) = hx;
    }
    for (int i = t; i < 32 * ZD; i += 256) {
        const int n = i / ZD;
        if (n0 + n < NN) zbuf[(size_t)n0 * ZD + i] = 0.f;
    }
    __syncthreads();

    s16x8 wf[4][4];
#pragma unroll
    for (int nt = 0; nt < 4; nt++)
#pragma unroll
        for (int ks = 0; ks < 4; ks++)
            wf[nt][ks] = *(const s16x8*)(WAB + (size_t)(w * 64 + nt * 16 + lr) * HD + ks * 32 + lg * 8);

    f32x4 acc[2][4];
#pragma unroll
    for (int nt = 0; nt < 4; nt++) {
        const int cc = w * 64 + nt * 16 + lr;
        const float bb = (cc < 128) ? b0[cc] : 0.f;
        f32x4 v; v[0] = bb; v[1] = bb; v[2] = bb; v[3] = bb;
        acc[0][nt] = v;
        acc[1][nt] = v;
    }
#pragma unroll
    for (int ks = 0; ks < 4; ks++) {
#pragma unroll
        for (int g = 0; g < 2; g++) {
            const s16x8 xf = *(const s16x8*)(xs + (g * 16 + lr) * 136 + ks * 32 + lg * 8);
#pragma unroll
            for (int nt = 0; nt < 4; nt++)
                acc[g][nt] = __builtin_amdgcn_mfma_f32_16x16x32_bf16(xf, wf[nt][ks], acc[g][nt], 0, 0, 0);
        }
    }
#pragma unroll
    for (int g = 0; g < 2; g++)
#pragma unroll
        for (int nt = 0; nt < 4; nt++) {
            const int cc = w * 64 + nt * 16 + lr;
#pragma unroll
            for (int r = 0; r < 4; r++) {
                const int node = n0 + g * 16 + lg * 4 + r;
                if (node < NN) {
                    const ushort val = f2bf(acc[g][nt][r]);
                    if (cc < 128) A[(size_t)node * HD + cc] = val;
                    else Bm[(size_t)node * HD + (cc - 128)] = val;
                }
            }
        }
}

// ---------------- persistent MFMA edge kernel (R13 winner, exact) ----------------
// C/D frag: col = lane&15 (B-operand row), row = (lane>>4)*4 + reg (A-operand row)  [m89/m91]
template<int DOUTB>
__global__ __launch_bounds__(256, 2)
void edge_mfma_kernel(const ushort* __restrict__ Af, const ushort* __restrict__ Bf,
                      const ushort* __restrict__ W1T, const float* __restrict__ b1,
                      const ushort* __restrict__ W2T, const float* __restrict__ b2,
                      const int* __restrict__ ssrc, const int* __restrict__ nof,
                      float* __restrict__ out) {
    __shared__ __align__(16) ushort HH1[TILE * 136];   // h1 [e][k]; later m [c][e]
    __shared__ __align__(16) ushort HH2[TILE * 136];   // h2 [e][c]
    __shared__ __align__(16) int s_node[2][TILE];

    const int t = threadIdx.x;
    const int lane = t & 63;
    const int w = t >> 6;
    const int lr = lane & 15;
    const int lg = lane >> 4;
    const int cg = t & 15;      // gather k-chunk
    const int eb = t >> 4;      // gather base edge (e_i = eb + 16*i)

    // ---- persistent weight fragments (once per block) ----
    s16x8 w1f[2][4];
#pragma unroll
    for (int m = 0; m < 2; m++)
#pragma unroll
        for (int ks = 0; ks < 4; ks++)
            w1f[m][ks] = *(const s16x8*)(W1T + (size_t)(w * 32 + m * 16 + lr) * HD + ks * 32 + lg * 8);

    constexpr int CT3 = (DOUTB == 128) ? 2 : 1;
    s16x8 w2f[CT3][4];
#pragma unroll
    for (int ct = 0; ct < CT3; ct++) {
        const int row = (DOUTB == 128) ? ((w * 2 + ct) * 16 + lr) : lr;
#pragma unroll
        for (int ks = 0; ks < 4; ks++)
            w2f[ct][ks] = *(const s16x8*)(W2T + (size_t)row * HD + ks * 32 + lg * 8);
    }

    float bias2[2][4];
#pragma unroll
    for (int m = 0; m < 2; m++)
#pragma unroll
        for (int r = 0; r < 4; r++)
            bias2[m][r] = b1[w * 32 + m * 16 + lg * 4 + r];
    float bias3[CT3];
#pragma unroll
    for (int ct = 0; ct < CT3; ct++)
        bias3[ct] = (DOUTB == 128) ? b2[(w * 2 + ct) * 16 + lr] : b2[lr];

    // ---- prologue: tile-0 indices + bv gathers ----
    int tile = blockIdx.x;
    int ts = tile * TILE;
    if (t < TILE) s_node[0][t] = nof[ts + t];
    int nd[8], sr[8];
#pragma unroll
    for (int i = 0; i < 8; i++) {
        const int e = eb + 16 * i;
        nd[i] = nof[ts + e];
        sr[i] = ssrc[ts + e];
    }
    s16x8 bv[8];
#pragma unroll
    for (int i = 0; i < 8; i++)
        bv[i] = *(const s16x8*)(Bf + (size_t)sr[i] * HD + cg * 8);
    int buf = 0;
    __syncthreads();

    for (; tile < NTILES; tile += gridDim.x) {
        ts = tile * TILE;
        const int tn = (tile + (int)gridDim.x < NTILES) ? (tile + (int)gridDim.x) : tile;
        const int tsn = tn * TILE;

        // ---- h1 fill: av on demand (dst-sorted -> L1-hot), bv prefetched ----
#pragma unroll
        for (int i = 0; i < 8; i++) {
            const int e = eb + 16 * i;
            const s16x8 av = *(const s16x8*)(Af + (size_t)nd[i] * HD + cg * 8);
            s16x8 hv;
#pragma unroll
            for (int j = 0; j < 8; j++)
                hv[j] = f2bf(fmaxf(bf2f(av[j]) + bf2f(bv[i][j]), 0.f));
            *(s16x8*)(HH1 + e * 136 + cg * 8) = hv;
        }
        __syncthreads();

        // ---- prefetch next-tile indices + s_node[buf^1] (land during L2) ----
#pragma unroll
        for (int i = 0; i < 8; i++) {
            const int e = eb + 16 * i;
            nd[i] = nof[tsn + e];
            sr[i] = ssrc[tsn + e];
        }
        if (t < TILE) s_node[buf ^ 1][t] = nof[tsn + t];

        // ---- layer 2: D[c][e], wave's 32-c slice x ALL 128 edges ----
        f32x4 acc[2][8];
#pragma unroll
        for (int m = 0; m < 2; m++)
#pragma unroll
            for (int n = 0; n < 8; n++) {
                f32x4 v; v[0] = bias2[m][0]; v[1] = bias2[m][1]; v[2] = bias2[m][2]; v[3] = bias2[m][3];
                acc[m][n] = v;
            }
#pragma unroll
        for (int ks = 0; ks < 4; ks++) {
            const int k0 = ks * 32 + lg * 8;
            s16x8 bfr[8];
#pragma unroll
            for (int n = 0; n < 8; n++)
                bfr[n] = *(const s16x8*)(HH1 + (n * 16 + lr) * 136 + k0);
#pragma unroll
            for (int m = 0; m < 2; m++)
#pragma unroll
                for (int n = 0; n < 8; n++)
                    acc[m][n] = __builtin_amdgcn_mfma_f32_16x16x32_bf16(w1f[m][ks], bfr[n], acc[m][n], 0, 0, 0);
        }
        // h2 = relu(acc) -> HH2[e][c]
#pragma unroll
        for (int m = 0; m < 2; m++)
#pragma unroll
            for (int n = 0; n < 8; n++) {
                const int e = n * 16 + lr;
                const int c0 = w * 32 + m * 16 + lg * 4;
                s16x4 hv;
                hv[0] = f2bf(fmaxf(acc[m][n][0], 0.f));
                hv[1] = f2bf(fmaxf(acc[m][n][1], 0.f));
                hv[2] = f2bf(fmaxf(acc[m][n][2], 0.f));
                hv[3] = f2bf(fmaxf(acc[m][n][3], 0.f));
                *(s16x4*)(HH2 + e * 136 + c0) = hv;
            }
        // ---- issue next-tile bv gathers (land during L3+agg) ----
#pragma unroll
        for (int i = 0; i < 8; i++)
            bv[i] = *(const s16x8*)(Bf + (size_t)sr[i] * HD + cg * 8);
        __syncthreads();   // h2 visible; all HH1 reads retired

        // ---- layer 3 (swapped operands): D[e][c]; m -> HH1 ----
        if constexpr (DOUTB == 128) {
            f32x4 acc3[8][2];
#pragma unroll
            for (int n = 0; n < 8; n++)
#pragma unroll
                for (int ct = 0; ct < 2; ct++) {
                    const float bb = bias3[ct];
                    f32x4 v; v[0] = bb; v[1] = bb; v[2] = bb; v[3] = bb;
                    acc3[n][ct] = v;
                }
#pragma unroll
            for (int ks = 0; ks < 4; ks++) {
                const int k0 = ks * 32 + lg * 8;
                s16x8 h2f[8];
#pragma unroll
                for (int n = 0; n < 8; n++)
                    h2f[n] = *(const s16x8*)(HH2 + (n * 16 + lr) * 136 + k0);
#pragma unroll
                for (int n = 0; n < 8; n++)
#pragma unroll
                    for (int ct = 0; ct < 2; ct++)
                        acc3[n][ct] = __builtin_amdgcn_mfma_f32_16x16x32_bf16(h2f[n], w2f[ct][ks], acc3[n][ct], 0, 0, 0);
            }
#pragma unroll
            for (int n = 0; n < 8; n++)
#pragma unroll
                for (int ct = 0; ct < 2; ct++) {
                    const int e0 = n * 16 + lg * 4;
                    const int c = (w * 2 + ct) * 16 + lr;
                    s16x4 mv;
                    mv[0] = f2bf(acc3[n][ct][0]);
                    mv[1] = f2bf(acc3[n][ct][1]);
                    mv[2] = f2bf(acc3[n][ct][2]);
                    mv[3] = f2bf(acc3[n][ct][3]);
                    *(s16x4*)(HH1 + c * 136 + e0) = mv;
                }
        } else {
            f32x4 acc3[2];
#pragma unroll
            for (int e2 = 0; e2 < 2; e2++) {
                const float bb = bias3[0];
                f32x4 v; v[0] = bb; v[1] = bb; v[2] = bb; v[3] = bb;
                acc3[e2] = v;
            }
#pragma unroll
            for (int ks = 0; ks < 4; ks++) {
                const int k0 = ks * 32 + lg * 8;
#pragma unroll
                for (int e2 = 0; e2 < 2; e2++) {
                    const s16x8 h2f = *(const s16x8*)(HH2 + ((w * 2 + e2) * 16 + lr) * 136 + k0);
                    acc3[e2] = __builtin_amdgcn_mfma_f32_16x16x32_bf16(h2f, w2f[0][ks], acc3[e2], 0, 0, 0);
                }
            }
#pragma unroll
            for (int e2 = 0; e2 < 2; e2++) {
                const int e0 = (w * 2 + e2) * 16 + lg * 4;
                const int c = lr;
                s16x4 mv;
                mv[0] = f2bf(acc3[e2][0]);
                mv[1] = f2bf(acc3[e2][1]);
                mv[2] = f2bf(acc3[e2][2]);
                mv[3] = f2bf(acc3[e2][3]);
                *(s16x4*)(HH1 + c * 136 + e0) = mv;
            }
        }
        __syncthreads();   // m visible

        // ---- aggregation via MFMA: out[slot][c] = Σ_e sel[slot][e] m[e][c] ----
        const int* sn = s_node[buf];
        const int nd0 = sn[0];
        const int ndL = sn[TILE - 1];
        if constexpr (DOUTB == 128) {
            if (ndL - nd0 <= 15) {
                f32x4 agg[2];
                agg[0] = (f32x4)0.f; agg[1] = (f32x4)0.f;
#pragma unroll
                for (int ks = 0; ks < 4; ks++) {
                    const int4 na = *(const int4*)&sn[ks * 32 + lg * 8];
                    const int4 nb = *(const int4*)&sn[ks * 32 + lg * 8 + 4];
                    s16x8 sel;
                    sel[0] = (na.x - nd0 == lr) ? (short)0x3F80 : (short)0;
                    sel[1] = (na.y - nd0 == lr) ? (short)0x3F80 : (short)0;
                    sel[2] = (na.z - nd0 == lr) ? (short)0x3F80 : (short)0;
                    sel[3] = (na.w - nd0 == lr) ? (short)0x3F80 : (short)0;
                    sel[4] = (nb.x - nd0 == lr) ? (short)0x3F80 : (short)0;
                    sel[5] = (nb.y - nd0 == lr) ? (short)0x3F80 : (short)0;
                    sel[6] = (nb.z - nd0 == lr) ? (short)0x3F80 : (short)0;
                    sel[7] = (nb.w - nd0 == lr) ? (short)0x3F80 : (short)0;
#pragma unroll
                    for (int ci = 0; ci < 2; ci++) {
                        const s16x8 mf = *(const s16x8*)(HH1 + ((w * 2 + ci) * 16 + lr) * 136 + ks * 32 + lg * 8);
                        agg[ci] = __builtin_amdgcn_mfma_f32_16x16x32_bf16(sel, mf, agg[ci], 0, 0, 0);
                    }
                }
#pragma unroll
                for (int ci = 0; ci < 2; ci++) {
                    const int c = (w * 2 + ci) * 16 + lr;
#pragma unroll
                    for (int r = 0; r < 4; r++) {
                        const int ndn = nd0 + lg * 4 + r;
                        if (ndn <= ndL) {
                            float* dp = out + (size_t)ndn * 128 + c;
                            const float v = agg[ci][r];
                            if (ndn > nd0 && ndn < ndL) *dp = v;
                            else atomicAdd(dp, v);
                        }
                    }
                }
            } else {
                for (int idx = t; idx < TILE * 128; idx += 256) {
                    const int e = idx >> 7, c = idx & 127;
                    atomicAdd(out + (size_t)sn[e] * 128 + c, bf2f(HH1[c * 136 + e]));
                }
            }
        } else {
            const int nw0 = sn[w * 32];
            const int nwL = sn[w * 32 + 31];
            if (nwL - nw0 <= 15) {
                const int4 na = *(const int4*)&sn[w * 32 + lg * 8];
                const int4 nb = *(const int4*)&sn[w * 32 + lg * 8 + 4];
                s16x8 sel;
                sel[0] = (na.x - nw0 == lr) ? (short)0x3F80 : (short)0;
                sel[1] = (na.y - nw0 == lr) ? (short)0x3F80 : (short)0;
                sel[2] = (na.z - nw0 == lr) ? (short)0x3F80 : (short)0;
                sel[3] = (na.w - nw0 == lr) ? (short)0x3F80 : (short)0;
                sel[4] = (nb.x - nw0 == lr) ? (short)0x3F80 : (short)0;
                sel[5] = (nb.y - nw0 == lr) ? (short)0x3F80 : (short)0;
                sel[6] = (nb.z - nw0 == lr) ? (short)0x3F80 : (short)0;
                sel[7] = (nb.w - nw0 == lr) ? (short)0x3F80 : (short)0;
                const s16x8 mf = *(const s16x8*)(HH1 + lr * 136 + w * 32 + lg * 8);
                f32x4 agg = (f32x4)0.f;
                agg = __builtin_amdgcn_mfma_f32_16x16x32_bf16(sel, mf, agg, 0, 0, 0);
#pragma unroll
                for (int r = 0; r < 4; r++) {
                    const int ndn = nw0 + lg * 4 + r;
                    if (ndn <= nwL) {
                        float* dp = out + (size_t)ndn * 16 + lr;
                        const float v = agg[r];
                        if (ndn > nw0 && ndn < nwL) *dp = v;
                        else atomicAdd(dp, v);
                    }
                }
            } else {
                for (int idx = lane; idx < 32 * 16; idx += 64) {
                    const int e = w * 32 + (idx >> 4), c = idx & 15;
                    atomicAdd(out + (size_t)sn[e] * 16 + c, bf2f(HH1[c * 136 + e]));
                }
            }
        }
        buf ^= 1;
        __syncthreads();   // agg reads retired before next h1 fill
    }
}

extern "C" void kernel_launch(void* const* d_in, const int* in_sizes, int n_in,
                              void* d_out, int out_size, void* d_ws, size_t ws_size,
                              hipStream_t stream) {
    const float* x = (const float*)d_in[0];
    const int* ei = (const int*)d_in[2];
    const int* src = ei;
    const int* dst = ei + NE;
    const float* W[4][3];
    const float* bs[4][3];
    for (int b = 0; b < 4; b++)
        for (int l = 0; l < 3; l++) {
            W[b][l]  = (const float*)d_in[4 + b * 6 + l * 2];
            bs[b][l] = (const float*)d_in[4 + b * 6 + l * 2 + 1];
        }

    float* x0   = (float*)d_ws;
    float* x1   = x0 + (size_t)NN * HD;
    ushort* A   = (ushort*)(x1 + (size_t)NN * HD);
    ushort* Bm  = A + (size_t)NN * HD;
    ushort* WT  = Bm + (size_t)NN * HD;       // 229376 ushort = 448 KB
    int* cnt    = (int*)(WT + 229376);
    int* rs     = cnt + NN;
    int* cur    = rs + NN + 1;
    int* ssrc   = cur + NN;
    int* nof    = ssrc + NE;
    float* out  = (float*)d_out;

    WPtrs wp;
    for (int b = 0; b < 4; b++) { wp.w[2 * b] = W[b][1]; wp.w[2 * b + 1] = W[b][2]; }
    for (int b = 1; b < 4; b++) wp.w0[b - 1] = W[b][0];

    prep_kernel<<<1505, 256, 0, stream>>>(x, W[0][0], bs[0][0], A, Bm, x0, wp, WT, cnt);
    hist_kernel<<<(NE + 255) / 256, 256, 0, stream>>>(dst, cnt);
    scan_kernel<<<1, 256, 0, stream>>>(cnt, rs, cur);
    scatter_kernel<<<(NE + 255) / 256, 256, 0, stream>>>(src, dst, cur, ssrc, nof);

    const ushort* W1T[4];
    const ushort* W2T[4];
    const ushort* WAB[4];
    for (int b = 0; b < 4; b++) { W1T[b] = WT + b * 16384; W2T[b] = WT + 65536 + b * 16384; }
    for (int b = 1; b < 4; b++) WAB[b] = WT + 131072 + (b - 1) * 32768;

    const int EG = 500;   // 5 tiles/block, 2 blocks/CU

    edge_mfma_kernel<128><<<EG, 256, 0, stream>>>(A, Bm, W1T[0], bs[0][1], W2T[0], bs[0][2], ssrc, nof, x0);
    nodeAB_mfma_kernel<<<(NN + 31) / 32, 256, 0, stream>>>(x0, WAB[1], bs[1][0], A, Bm, x1, 128);
    edge_mfma_kernel<128><<<EG, 256, 0, stream>>>(A, Bm, W1T[1], bs[1][1], W2T[1], bs[1][2], ssrc, nof, x1);
    nodeAB_mfma_kernel<<<(NN + 31) / 32, 256, 0, stream>>>(x1, WAB[2], bs[2][0], A, Bm, x0, 128);
    edge_mfma_kernel<128><<<EG, 256, 0, stream>>>(A, Bm, W1T[2], bs[2][1], W2T[2], bs[2][2], ssrc, nof, x0);
    nodeAB_mfma_kernel<<<(NN + 31) / 32, 256, 0, stream>>>(x0, WAB[3], bs[3][0], A, Bm, out, 16);
    edge_mfma_kernel<16><<<EG, 256, 0, stream>>>(A, Bm, W1T[3], bs[3][1], W2T[3], bs[3][2], ssrc, nof, out);
}

// Round 18
// 251.902 us; speedup vs baseline: 1.6857x; 1.0298x over previous
//
#include <hip/hip_runtime.h>
#include <hip/hip_bf16.h>

#define NN 10000
#define NE 320000
#define HD 128
#define TILE 128
#define NTILES (NE / TILE)   // 2500 exactly

typedef __attribute__((ext_vector_type(8))) short s16x8;
typedef __attribute__((ext_vector_type(4))) short s16x4;
typedef __attribute__((ext_vector_type(4))) float f32x4;

__device__ __forceinline__ ushort f2bf(float f) {
    union { __hip_bfloat16 b; ushort u; } v;
    v.b = __float2bfloat16(f);   // HW cvt (RNE) on gfx950
    return v.u;
}
__device__ __forceinline__ float bf2f(short s) {
    union { unsigned u; float f; } v;
    v.u = ((unsigned)(unsigned short)s) << 16;
    return v.f;
}

struct WPtrs { const float* w[8]; const float* w0[3]; };

// ---------------- fused prep: nodeAB block-0 + weight prep + cnt zero ----------------
__global__ __launch_bounds__(256)
void prep_kernel(const float* __restrict__ x, const float* __restrict__ W00,
                 const float* __restrict__ b00, ushort* __restrict__ A,
                 ushort* __restrict__ Bm, float* __restrict__ x0,
                 WPtrs p, ushort* __restrict__ wdst, int* __restrict__ cnt) {
    __shared__ float xs[16 * 128];
    const int blk = blockIdx.x;
    const int t = threadIdx.x;
    if (blk < 625) {
        const int n0 = blk * 16;
        for (int i = t; i < 16 * 4; i += 256) {
            int n = i / 4, d = i % 4;
            xs[n * 128 + d] = x[(size_t)(n0 + n) * 4 + d];
        }
        for (int i = t; i < 16 * 128; i += 256) x0[(size_t)n0 * 128 + i] = 0.f;
        __syncthreads();
        int c = t & 127;
        int h = t >> 7;
        float a[8], b[8];
        float bias = b00[c];
#pragma unroll
        for (int n = 0; n < 8; n++) { a[n] = bias; b[n] = 0.f; }
#pragma unroll
        for (int d = 0; d < 4; d++) {
            float wt = W00[d * HD + c];
            float wb = W00[(4 + d) * HD + c];
            float wd = wt - wb;
#pragma unroll
            for (int n = 0; n < 8; n++) {
                float xv = xs[(h * 8 + n) * 128 + d];
                a[n] += xv * wd;
                b[n] += xv * wb;
            }
        }
#pragma unroll
        for (int n = 0; n < 8; n++) {
            int gn = n0 + h * 8 + n;
            A[(size_t)gn * HD + c] = f2bf(a[n]);
            Bm[(size_t)gn * HD + c] = f2bf(b[n]);
        }
    } else if (blk < 1465) {
        int tid = (blk - 625) * 256 + t;
        if (tid < 7 * 16384) {
            int m = tid >> 14, idx = tid & 16383;
            int b = m >> 1, l = m & 1;
            int k = idx / 128, c = idx % 128;
            wdst[l * 65536 + b * 16384 + c * 128 + k] = f2bf(p.w[m][k * 128 + c]);
        } else if (tid < 7 * 16384 + 2048) {
            int idx = tid - 7 * 16384;
            int k = idx / 16, c = idx % 16;
            wdst[65536 + 3 * 16384 + c * 128 + k] = f2bf(p.w[7][k * 16 + c]);
        } else {
            int q = tid - 116736;
            int b = q >> 15, r = q & 32767;
            int cc = r >> 7, d = r & 127;
            const float* w0 = p.w0[b];
            float val = (cc < 128) ? (w0[d * 128 + cc] - w0[(128 + d) * 128 + cc])
                                   : w0[(128 + d) * 128 + (cc - 128)];
            wdst[131072 + b * 32768 + cc * 128 + d] = f2bf(val);
        }
    } else {
        int i = (blk - 1465) * 256 + t;
        if (i < NN) cnt[i] = 0;
    }
}

// ---------------- CSR build (edges sorted by dst) ----------------
__global__ void hist_kernel(const int* __restrict__ dst, int* __restrict__ cnt) {
    int e = blockIdx.x * blockDim.x + threadIdx.x;
    if (e < NE) atomicAdd(&cnt[dst[e]], 1);
}

// exclusive-scan into cur only (rs was dead since nodeof_kernel removal)
__global__ void scan_kernel(const int* __restrict__ cnt, int* __restrict__ cur) {
    __shared__ int part[256];
    int t = threadIdx.x;
    const int CH = (NN + 255) / 256;  // 40
    int base = t * CH;
    int s = 0;
    for (int i = 0; i < CH; i++) {
        int idx = base + i;
        if (idx < NN) s += cnt[idx];
    }
    part[t] = s;
    __syncthreads();
    for (int off = 1; off < 256; off <<= 1) {
        int v = (t >= off) ? part[t - off] : 0;
        __syncthreads();
        part[t] += v;
        __syncthreads();
    }
    int run = part[t] - s;
    for (int i = 0; i < CH; i++) {
        int idx = base + i;
        if (idx < NN) {
            cur[idx] = run;
            run += cnt[idx];
        }
    }
}

__global__ void scatter_kernel(const int* __restrict__ src, const int* __restrict__ dst,
                               int* __restrict__ cur, int* __restrict__ ssrc,
                               int* __restrict__ nof) {
    int e = blockIdx.x * blockDim.x + threadIdx.x;
    if (e < NE) {
        int d = dst[e];
        int p = atomicAdd(&cur[d], 1);
        ssrc[p] = src[e];
        nof[p] = d;
    }
}

// ---------------- blocks 1-3 layer-1 via MFMA: 32 nodes/block x 256 outs x K=128 ----------------
__global__ __launch_bounds__(256)
void nodeAB_mfma_kernel(const float* __restrict__ xin, const ushort* __restrict__ WAB,
                        const float* __restrict__ b0, ushort* __restrict__ A,
                        ushort* __restrict__ Bm, float* __restrict__ zbuf, int ZD) {
    __shared__ __align__(16) ushort xs[32 * 136];
    const int t = threadIdx.x, lane = t & 63, w = t >> 6, lr = lane & 15, lg = lane >> 4;
    const int n0 = blockIdx.x * 32;

    for (int i = t; i < 1024; i += 256) {
        const int n = i >> 5, s4 = i & 31;
        const float4 xv = *(const float4*)(xin + (size_t)(n0 + n) * HD + s4 * 4);
        s16x4 hx;
        hx[0] = f2bf(xv.x); hx[1] = f2bf(xv.y); hx[2] = f2bf(xv.z); hx[3] = f2bf(xv.w);
        *(s16x4*)(xs + n * 136 + s4 * 4) = hx;
    }
    for (int i = t; i < 32 * ZD; i += 256) {
        const int n = i / ZD;
        if (n0 + n < NN) zbuf[(size_t)n0 * ZD + i] = 0.f;
    }
    __syncthreads();

    s16x8 wf[4][4];
#pragma unroll
    for (int nt = 0; nt < 4; nt++)
#pragma unroll
        for (int ks = 0; ks < 4; ks++)
            wf[nt][ks] = *(const s16x8*)(WAB + (size_t)(w * 64 + nt * 16 + lr) * HD + ks * 32 + lg * 8);

    f32x4 acc[2][4];
#pragma unroll
    for (int nt = 0; nt < 4; nt++) {
        const int cc = w * 64 + nt * 16 + lr;
        const float bb = (cc < 128) ? b0[cc] : 0.f;
        f32x4 v; v[0] = bb; v[1] = bb; v[2] = bb; v[3] = bb;
        acc[0][nt] = v;
        acc[1][nt] = v;
    }
#pragma unroll
    for (int ks = 0; ks < 4; ks++) {
#pragma unroll
        for (int g = 0; g < 2; g++) {
            const s16x8 xf = *(const s16x8*)(xs + (g * 16 + lr) * 136 + ks * 32 + lg * 8);
#pragma unroll
            for (int nt = 0; nt < 4; nt++)
                acc[g][nt] = __builtin_amdgcn_mfma_f32_16x16x32_bf16(xf, wf[nt][ks], acc[g][nt], 0, 0, 0);
        }
    }
#pragma unroll
    for (int g = 0; g < 2; g++)
#pragma unroll
        for (int nt = 0; nt < 4; nt++) {
            const int cc = w * 64 + nt * 16 + lr;
#pragma unroll
            for (int r = 0; r < 4; r++) {
                const int node = n0 + g * 16 + lg * 4 + r;
                if (node < NN) {
                    const ushort val = f2bf(acc[g][nt][r]);
                    if (cc < 128) A[(size_t)node * HD + cc] = val;
                    else Bm[(size_t)node * HD + (cc - 128)] = val;
                }
            }
        }
}

// ---------------- persistent MFMA edge kernel (R13 winner, exact) ----------------
// C/D frag: col = lane&15 (B-operand row), row = (lane>>4)*4 + reg (A-operand row)  [m89/m91]
template<int DOUTB>
__global__ __launch_bounds__(256, 2)
void edge_mfma_kernel(const ushort* __restrict__ Af, const ushort* __restrict__ Bf,
                      const ushort* __restrict__ W1T, const float* __restrict__ b1,
                      const ushort* __restrict__ W2T, const float* __restrict__ b2,
                      const int* __restrict__ ssrc, const int* __restrict__ nof,
                      float* __restrict__ out) {
    __shared__ __align__(16) ushort HH1[TILE * 136];   // h1 [e][k]; later m [c][e]
    __shared__ __align__(16) ushort HH2[TILE * 136];   // h2 [e][c]
    __shared__ __align__(16) int s_node[2][TILE];

    const int t = threadIdx.x;
    const int lane = t & 63;
    const int w = t >> 6;
    const int lr = lane & 15;
    const int lg = lane >> 4;
    const int cg = t & 15;      // gather k-chunk
    const int eb = t >> 4;      // gather base edge (e_i = eb + 16*i)

    // ---- persistent weight fragments (once per block) ----
    s16x8 w1f[2][4];
#pragma unroll
    for (int m = 0; m < 2; m++)
#pragma unroll
        for (int ks = 0; ks < 4; ks++)
            w1f[m][ks] = *(const s16x8*)(W1T + (size_t)(w * 32 + m * 16 + lr) * HD + ks * 32 + lg * 8);

    constexpr int CT3 = (DOUTB == 128) ? 2 : 1;
    s16x8 w2f[CT3][4];
#pragma unroll
    for (int ct = 0; ct < CT3; ct++) {
        const int row = (DOUTB == 128) ? ((w * 2 + ct) * 16 + lr) : lr;
#pragma unroll
        for (int ks = 0; ks < 4; ks++)
            w2f[ct][ks] = *(const s16x8*)(W2T + (size_t)row * HD + ks * 32 + lg * 8);
    }

    float bias2[2][4];
#pragma unroll
    for (int m = 0; m < 2; m++)
#pragma unroll
        for (int r = 0; r < 4; r++)
            bias2[m][r] = b1[w * 32 + m * 16 + lg * 4 + r];
    float bias3[CT3];
#pragma unroll
    for (int ct = 0; ct < CT3; ct++)
        bias3[ct] = (DOUTB == 128) ? b2[(w * 2 + ct) * 16 + lr] : b2[lr];

    // ---- prologue: tile-0 indices + bv gathers ----
    int tile = blockIdx.x;
    int ts = tile * TILE;
    if (t < TILE) s_node[0][t] = nof[ts + t];
    int nd[8], sr[8];
#pragma unroll
    for (int i = 0; i < 8; i++) {
        const int e = eb + 16 * i;
        nd[i] = nof[ts + e];
        sr[i] = ssrc[ts + e];
    }
    s16x8 bv[8];
#pragma unroll
    for (int i = 0; i < 8; i++)
        bv[i] = *(const s16x8*)(Bf + (size_t)sr[i] * HD + cg * 8);
    int buf = 0;
    __syncthreads();

    for (; tile < NTILES; tile += gridDim.x) {
        ts = tile * TILE;
        const int tn = (tile + (int)gridDim.x < NTILES) ? (tile + (int)gridDim.x) : tile;
        const int tsn = tn * TILE;

        // ---- h1 fill: av on demand (dst-sorted -> L1-hot), bv prefetched ----
#pragma unroll
        for (int i = 0; i < 8; i++) {
            const int e = eb + 16 * i;
            const s16x8 av = *(const s16x8*)(Af + (size_t)nd[i] * HD + cg * 8);
            s16x8 hv;
#pragma unroll
            for (int j = 0; j < 8; j++)
                hv[j] = f2bf(fmaxf(bf2f(av[j]) + bf2f(bv[i][j]), 0.f));
            *(s16x8*)(HH1 + e * 136 + cg * 8) = hv;
        }
        __syncthreads();

        // ---- prefetch next-tile indices + s_node[buf^1] (land during L2) ----
#pragma unroll
        for (int i = 0; i < 8; i++) {
            const int e = eb + 16 * i;
            nd[i] = nof[tsn + e];
            sr[i] = ssrc[tsn + e];
        }
        if (t < TILE) s_node[buf ^ 1][t] = nof[tsn + t];

        // ---- layer 2: D[c][e], wave's 32-c slice x ALL 128 edges ----
        f32x4 acc[2][8];
#pragma unroll
        for (int m = 0; m < 2; m++)
#pragma unroll
            for (int n = 0; n < 8; n++) {
                f32x4 v; v[0] = bias2[m][0]; v[1] = bias2[m][1]; v[2] = bias2[m][2]; v[3] = bias2[m][3];
                acc[m][n] = v;
            }
#pragma unroll
        for (int ks = 0; ks < 4; ks++) {
            const int k0 = ks * 32 + lg * 8;
            s16x8 bfr[8];
#pragma unroll
            for (int n = 0; n < 8; n++)
                bfr[n] = *(const s16x8*)(HH1 + (n * 16 + lr) * 136 + k0);
#pragma unroll
            for (int m = 0; m < 2; m++)
#pragma unroll
                for (int n = 0; n < 8; n++)
                    acc[m][n] = __builtin_amdgcn_mfma_f32_16x16x32_bf16(w1f[m][ks], bfr[n], acc[m][n], 0, 0, 0);
        }
        // h2 = relu(acc) -> HH2[e][c]
#pragma unroll
        for (int m = 0; m < 2; m++)
#pragma unroll
            for (int n = 0; n < 8; n++) {
                const int e = n * 16 + lr;
                const int c0 = w * 32 + m * 16 + lg * 4;
                s16x4 hv;
                hv[0] = f2bf(fmaxf(acc[m][n][0], 0.f));
                hv[1] = f2bf(fmaxf(acc[m][n][1], 0.f));
                hv[2] = f2bf(fmaxf(acc[m][n][2], 0.f));
                hv[3] = f2bf(fmaxf(acc[m][n][3], 0.f));
                *(s16x4*)(HH2 + e * 136 + c0) = hv;
            }
        // ---- issue next-tile bv gathers (land during L3+agg) ----
#pragma unroll
        for (int i = 0; i < 8; i++)
            bv[i] = *(const s16x8*)(Bf + (size_t)sr[i] * HD + cg * 8);
        __syncthreads();   // h2 visible; all HH1 reads retired

        // ---- layer 3 (swapped operands): D[e][c]; m -> HH1 ----
        if constexpr (DOUTB == 128) {
            f32x4 acc3[8][2];
#pragma unroll
            for (int n = 0; n < 8; n++)
#pragma unroll
                for (int ct = 0; ct < 2; ct++) {
                    const float bb = bias3[ct];
                    f32x4 v; v[0] = bb; v[1] = bb; v[2] = bb; v[3] = bb;
                    acc3[n][ct] = v;
                }
#pragma unroll
            for (int ks = 0; ks < 4; ks++) {
                const int k0 = ks * 32 + lg * 8;
                s16x8 h2f[8];
#pragma unroll
                for (int n = 0; n < 8; n++)
                    h2f[n] = *(const s16x8*)(HH2 + (n * 16 + lr) * 136 + k0);
#pragma unroll
                for (int n = 0; n < 8; n++)
#pragma unroll
                    for (int ct = 0; ct < 2; ct++)
                        acc3[n][ct] = __builtin_amdgcn_mfma_f32_16x16x32_bf16(h2f[n], w2f[ct][ks], acc3[n][ct], 0, 0, 0);
            }
#pragma unroll
            for (int n = 0; n < 8; n++)
#pragma unroll
                for (int ct = 0; ct < 2; ct++) {
                    const int e0 = n * 16 + lg * 4;
                    const int c = (w * 2 + ct) * 16 + lr;
                    s16x4 mv;
                    mv[0] = f2bf(acc3[n][ct][0]);
                    mv[1] = f2bf(acc3[n][ct][1]);
                    mv[2] = f2bf(acc3[n][ct][2]);
                    mv[3] = f2bf(acc3[n][ct][3]);
                    *(s16x4*)(HH1 + c * 136 + e0) = mv;
                }
        } else {
            f32x4 acc3[2];
#pragma unroll
            for (int e2 = 0; e2 < 2; e2++) {
                const float bb = bias3[0];
                f32x4 v; v[0] = bb; v[1] = bb; v[2] = bb; v[3] = bb;
                acc3[e2] = v;
            }
#pragma unroll
            for (int ks = 0; ks < 4; ks++) {
                const int k0 = ks * 32 + lg * 8;
#pragma unroll
                for (int e2 = 0; e2 < 2; e2++) {
                    const s16x8 h2f = *(const s16x8*)(HH2 + ((w * 2 + e2) * 16 + lr) * 136 + k0);
                    acc3[e2] = __builtin_amdgcn_mfma_f32_16x16x32_bf16(h2f, w2f[0][ks], acc3[e2], 0, 0, 0);
                }
            }
#pragma unroll
            for (int e2 = 0; e2 < 2; e2++) {
                const int e0 = (w * 2 + e2) * 16 + lg * 4;
                const int c = lr;
                s16x4 mv;
                mv[0] = f2bf(acc3[e2][0]);
                mv[1] = f2bf(acc3[e2][1]);
                mv[2] = f2bf(acc3[e2][2]);
                mv[3] = f2bf(acc3[e2][3]);
                *(s16x4*)(HH1 + c * 136 + e0) = mv;
            }
        }
        __syncthreads();   // m visible

        // ---- aggregation via MFMA: out[slot][c] = Σ_e sel[slot][e] m[e][c] ----
        const int* sn = s_node[buf];
        const int nd0 = sn[0];
        const int ndL = sn[TILE - 1];
        if constexpr (DOUTB == 128) {
            if (ndL - nd0 <= 15) {
                f32x4 agg[2];
                agg[0] = (f32x4)0.f; agg[1] = (f32x4)0.f;
#pragma unroll
                for (int ks = 0; ks < 4; ks++) {
                    const int4 na = *(const int4*)&sn[ks * 32 + lg * 8];
                    const int4 nb = *(const int4*)&sn[ks * 32 + lg * 8 + 4];
                    s16x8 sel;
                    sel[0] = (na.x - nd0 == lr) ? (short)0x3F80 : (short)0;
                    sel[1] = (na.y - nd0 == lr) ? (short)0x3F80 : (short)0;
                    sel[2] = (na.z - nd0 == lr) ? (short)0x3F80 : (short)0;
                    sel[3] = (na.w - nd0 == lr) ? (short)0x3F80 : (short)0;
                    sel[4] = (nb.x - nd0 == lr) ? (short)0x3F80 : (short)0;
                    sel[5] = (nb.y - nd0 == lr) ? (short)0x3F80 : (short)0;
                    sel[6] = (nb.z - nd0 == lr) ? (short)0x3F80 : (short)0;
                    sel[7] = (nb.w - nd0 == lr) ? (short)0x3F80 : (short)0;
#pragma unroll
                    for (int ci = 0; ci < 2; ci++) {
                        const s16x8 mf = *(const s16x8*)(HH1 + ((w * 2 + ci) * 16 + lr) * 136 + ks * 32 + lg * 8);
                        agg[ci] = __builtin_amdgcn_mfma_f32_16x16x32_bf16(sel, mf, agg[ci], 0, 0, 0);
                    }
                }
#pragma unroll
                for (int ci = 0; ci < 2; ci++) {
                    const int c = (w * 2 + ci) * 16 + lr;
#pragma unroll
                    for (int r = 0; r < 4; r++) {
                        const int ndn = nd0 + lg * 4 + r;
                        if (ndn <= ndL) {
                            float* dp = out + (size_t)ndn * 128 + c;
                            const float v = agg[ci][r];
                            if (ndn > nd0 && ndn < ndL) *dp = v;
                            else atomicAdd(dp, v);
                        }
                    }
                }
            } else {
                for (int idx = t; idx < TILE * 128; idx += 256) {
                    const int e = idx >> 7, c = idx & 127;
                    atomicAdd(out + (size_t)sn[e] * 128 + c, bf2f(HH1[c * 136 + e]));
                }
            }
        } else {
            const int nw0 = sn[w * 32];
            const int nwL = sn[w * 32 + 31];
            if (nwL - nw0 <= 15) {
                const int4 na = *(const int4*)&sn[w * 32 + lg * 8];
                const int4 nb = *(const int4*)&sn[w * 32 + lg * 8 + 4];
                s16x8 sel;
                sel[0] = (na.x - nw0 == lr) ? (short)0x3F80 : (short)0;
                sel[1] = (na.y - nw0 == lr) ? (short)0x3F80 : (short)0;
                sel[2] = (na.z - nw0 == lr) ? (short)0x3F80 : (short)0;
                sel[3] = (na.w - nw0 == lr) ? (short)0x3F80 : (short)0;
                sel[4] = (nb.x - nw0 == lr) ? (short)0x3F80 : (short)0;
                sel[5] = (nb.y - nw0 == lr) ? (short)0x3F80 : (short)0;
                sel[6] = (nb.z - nw0 == lr) ? (short)0x3F80 : (short)0;
                sel[7] = (nb.w - nw0 == lr) ? (short)0x3F80 : (short)0;
                const s16x8 mf = *(const s16x8*)(HH1 + lr * 136 + w * 32 + lg * 8);
                f32x4 agg = (f32x4)0.f;
                agg = __builtin_amdgcn_mfma_f32_16x16x32_bf16(sel, mf, agg, 0, 0, 0);
#pragma unroll
                for (int r = 0; r < 4; r++) {
                    const int ndn = nw0 + lg * 4 + r;
                    if (ndn <= nwL) {
                        float* dp = out + (size_t)ndn * 16 + lr;
                        const float v = agg[r];
                        if (ndn > nw0 && ndn < nwL) *dp = v;
                        else atomicAdd(dp, v);
                    }
                }
            } else {
                for (int idx = lane; idx < 32 * 16; idx += 64) {
                    const int e = w * 32 + (idx >> 4), c = idx & 15;
                    atomicAdd(out + (size_t)sn[e] * 16 + c, bf2f(HH1[c * 136 + e]));
                }
            }
        }
        buf ^= 1;
        __syncthreads();   // agg reads retired before next h1 fill
    }
}

extern "C" void kernel_launch(void* const* d_in, const int* in_sizes, int n_in,
                              void* d_out, int out_size, void* d_ws, size_t ws_size,
                              hipStream_t stream) {
    const float* x = (const float*)d_in[0];
    const int* ei = (const int*)d_in[2];
    const int* src = ei;
    const int* dst = ei + NE;
    const float* W[4][3];
    const float* bs[4][3];
    for (int b = 0; b < 4; b++)
        for (int l = 0; l < 3; l++) {
            W[b][l]  = (const float*)d_in[4 + b * 6 + l * 2];
            bs[b][l] = (const float*)d_in[4 + b * 6 + l * 2 + 1];
        }

    float* x0   = (float*)d_ws;
    float* x1   = x0 + (size_t)NN * HD;
    ushort* A   = (ushort*)(x1 + (size_t)NN * HD);
    ushort* Bm  = A + (size_t)NN * HD;
    ushort* WT  = Bm + (size_t)NN * HD;       // 229376 ushort = 448 KB
    int* cnt    = (int*)(WT + 229376);
    int* cur    = cnt + NN;
    int* ssrc   = cur + NN;
    int* nof    = ssrc + NE;
    float* out  = (float*)d_out;

    WPtrs wp;
    for (int b = 0; b < 4; b++) { wp.w[2 * b] = W[b][1]; wp.w[2 * b + 1] = W[b][2]; }
    for (int b = 1; b < 4; b++) wp.w0[b - 1] = W[b][0];

    prep_kernel<<<1505, 256, 0, stream>>>(x, W[0][0], bs[0][0], A, Bm, x0, wp, WT, cnt);
    hist_kernel<<<(NE + 255) / 256, 256, 0, stream>>>(dst, cnt);
    scan_kernel<<<1, 256, 0, stream>>>(cnt, cur);
    scatter_kernel<<<(NE + 255) / 256, 256, 0, stream>>>(src, dst, cur, ssrc, nof);

    const ushort* W1T[4];
    const ushort* W2T[4];
    const ushort* WAB[4];
    for (int b = 0; b < 4; b++) { W1T[b] = WT + b * 16384; W2T[b] = WT + 65536 + b * 16384; }
    for (int b = 1; b < 4; b++) WAB[b] = WT + 131072 + (b - 1) * 32768;

    const int EG = 500;   // 5 tiles/block, 2 blocks/CU

    edge_mfma_kernel<128><<<EG, 256, 0, stream>>>(A, Bm, W1T[0], bs[0][1], W2T[0], bs[0][2], ssrc, nof, x0);
    nodeAB_mfma_kernel<<<(NN + 31) / 32, 256, 0, stream>>>(x0, WAB[1], bs[1][0], A, Bm, x1, 128);
    edge_mfma_kernel<128><<<EG, 256, 0, stream>>>(A, Bm, W1T[1], bs[1][1], W2T[1], bs[1][2], ssrc, nof, x1);
    nodeAB_mfma_kernel<<<(NN + 31) / 32, 256, 0, stream>>>(x1, WAB[2], bs[2][0], A, Bm, x0, 128);
    edge_mfma_kernel<128><<<EG, 256, 0, stream>>>(A, Bm, W1T[2], bs[2][1], W2T[2], bs[2][2], ssrc, nof, x0);
    nodeAB_mfma_kernel<<<(NN + 31) / 32, 256, 0, stream>>>(x0, WAB[3], bs[3][0], A, Bm, out, 16);
    edge_mfma_kernel<16><<<EG, 256, 0, stream>>>(A, Bm, W1T[3], bs[3][1], W2T[3], bs[3][2], ssrc, nof, out);
}